// Round 20
// baseline (152.474 us; speedup 1.0000x reference)
//
#include <hip/hip_runtime.h>

#define TB 256
#define NGRP 8            // XCDs on MI355X
#define NB_P 1024         // partition blocks
#define TBP 256           // partition block threads
#define NBKT 512          // dst-range buckets (64 per XCD)
#define SORT_T 1024
#define STG_CAP 8192      // LDS staging entries in k_bsort (32 KB)
#define STG2_CAP 3200     // LDS staging entries in k_scatter
#define RCAP 4            // register-cached int4 chunks per thread in scatter
#define RB 8              // register-cached pk entries per thread in bsort

typedef int      i4v __attribute__((ext_vector_type(4)));
typedef float    f4v __attribute__((ext_vector_type(4)));
typedef _Float16 h4v __attribute__((ext_vector_type(4)));
typedef _Float16 h8v __attribute__((ext_vector_type(8)));

// Packed gather records: one cache line fetch per edge.
struct __align__(16) Rec2 { _Float16 h[8]; float as[2]; float pad[2]; };  // 32 B
struct __align__(16) Rec3 { _Float16 h[4]; float as; float pad; };        // 16 B

static __device__ __forceinline__ float leaky(float x) {
  return x > 0.f ? x : 0.2f * x;
}

// ========== fused single-pass scatter + node1 ==========
// Blocks [0,NB_P): edge-chunk counting-sort into private region with per-wave
// bucket cursors (512 buckets; layout phase handles 2 buckets/thread);
// LDS staging + coalesced flush. Blocks [NB_P,...): x@W1.

__global__ void __launch_bounds__(TB)
k_scatter_node1(const int* __restrict__ srcA, const int* __restrict__ dstA,
                int* __restrict__ cnt, int* __restrict__ loffG,
                int* __restrict__ epkPriv, int E4, int E, unsigned M, int R,
                int CH4, int CHP,
                const float* __restrict__ xin, const float* __restrict__ W1,
                const float* __restrict__ a_src, const float* __restrict__ a_dst,
                _Float16* __restrict__ hout, float* __restrict__ ad_, int N) {
  __shared__ __align__(16) char smem[23424];
  const int t = threadIdx.x;
  if (blockIdx.x < NB_P) {
    const int kblk = blockIdx.x;
    int* lc   = (int*)smem;                 // 4*NBKT: sub-hists, then per-wave cursors (8 KB)
    int* loff = (int*)(smem + 8192);        // NBKT+1
    int* stg  = (int*)(smem + 10304);       // STG2_CAP
    for (int i = t; i < 4 * NBKT; i += TBP) lc[i] = 0;
    __syncthreads();
    int* lcw = lc + (t >> 6) * NBKT;
    const int bstart = kblk * CH4;
    const int bend = min(E4, bstart + CH4);
    const i4v* d4 = reinterpret_cast<const i4v*>(dstA);
    const i4v* s4 = reinterpret_cast<const i4v*>(srcA);
    i4v dr[RCAP], sr[RCAP];
    // pass 1: load chunk into registers + per-wave histogram
    int it1 = 0;
    for (int i = bstart + t; i < bend; i += TBP, ++it1) {
      i4v d = __builtin_nontemporal_load(&d4[i]);
      i4v sv = __builtin_nontemporal_load(&s4[i]);
      if (it1 < RCAP) { dr[it1] = d; sr[it1] = sv; }
#pragma unroll
      for (int k = 0; k < 4; ++k) atomicAdd(&lcw[__umulhi((unsigned)d[k], M)], 1);
    }
    if (kblk == NB_P - 1) {
      for (int i = E4 * 4 + t; i < E; i += TBP)
        atomicAdd(&lcw[__umulhi((unsigned)dstA[i], M)], 1);
    }
    __syncthreads();
    // reduce sub-hists (2 buckets/thread) + exclusive scan -> bucket layout
    int cA0[2], cA1[2], cA2[2], cA3[2], cT[2];
#pragma unroll
    for (int hh = 0; hh < 2; ++hh) {
      const int bb = t + hh * TBP;
      cA0[hh] = lc[bb];
      cA1[hh] = lc[NBKT + bb];
      cA2[hh] = lc[2 * NBKT + bb];
      cA3[hh] = lc[3 * NBKT + bb];
      cT[hh] = cA0[hh] + cA1[hh] + cA2[hh] + cA3[hh];
      loff[bb] = cT[hh];
    }
    __syncthreads();
    for (int o = 1; o < NBKT; o <<= 1) {
      int u0 = (t >= o) ? loff[t - o] : 0;
      int u1 = (t + TBP >= o) ? loff[t + TBP - o] : 0;
      __syncthreads();
      loff[t] += u0;
      loff[t + TBP] += u1;
      __syncthreads();
    }
    int excl[2];
#pragma unroll
    for (int hh = 0; hh < 2; ++hh) excl[hh] = loff[t + hh * TBP] - cT[hh];
    __syncthreads();
#pragma unroll
    for (int hh = 0; hh < 2; ++hh) {
      const int bb = t + hh * TBP;
      cnt[bb * NB_P + kblk] = cT[hh];       // [bucket][block] for bscan1
      loffG[kblk * NBKT + bb] = excl[hh];   // block-major local offsets
      if (bb == NBKT - 1) loff[NBKT] = excl[hh] + cT[hh];
      // per-wave cursor bases (overwrite sub-hists in place)
      lc[bb] = excl[hh];
      lc[NBKT + bb] = excl[hh] + cA0[hh];
      lc[2 * NBKT + bb] = excl[hh] + cA0[hh] + cA1[hh];
      lc[3 * NBKT + bb] = excl[hh] + cA0[hh] + cA1[hh] + cA2[hh];
    }
    __syncthreads();
    // pass 2: scatter packed edges into LDS by bucket, per-wave cursors
    int it2 = 0;
    for (int i = bstart + t; i < bend; i += TBP, ++it2) {
      i4v d = (it2 < RCAP) ? dr[it2] : d4[i];
      i4v sv = (it2 < RCAP) ? sr[it2] : s4[i];
#pragma unroll
      for (int k = 0; k < 4; ++k) {
        int dd = d[k];
        int b = __umulhi((unsigned)dd, M);
        int pos = atomicAdd(&lcw[b], 1);
        stg[pos] = ((dd - b * R) << 17) | sv[k];
      }
    }
    if (kblk == NB_P - 1) {
      for (int i = E4 * 4 + t; i < E; i += TBP) {
        int dd = dstA[i];
        int b = __umulhi((unsigned)dd, M);
        int pos = atomicAdd(&lcw[b], 1);
        stg[pos] = ((dd - b * R) << 17) | srcA[i];
      }
    }
    __syncthreads();
    // linear coalesced flush to private region
    const int total = loff[NBKT];
    int* dst = epkPriv + (size_t)kblk * CHP;
    for (int i = t; i < total; i += TBP) dst[i] = stg[i];
  } else {
    // ---- node transform layer 1: IN=128, H=2, C=8, SPLIT=4 ----
    constexpr int IN = 128, OUT = 16, SPLIT = 4, NPB = TB / SPLIT, PIN4 = IN / SPLIT / 4;
    float* Ws = (float*)smem;
    float* Ad = (float*)(smem + 8192);
    const int bid = blockIdx.x - NB_P;
    for (int i = t; i < IN * OUT; i += TB) Ws[i] = W1[i];
    if (t < OUT) Ad[t] = a_dst[t];
    __syncthreads();
    const int j = t & (SPLIT - 1);
    const int n = bid * NPB + t / SPLIT;
    if (n >= N) return;
    float acc[OUT];
#pragma unroll
    for (int q = 0; q < OUT; ++q) acc[q] = 0.f;
    const f4v* x4 = reinterpret_cast<const f4v*>(xin + (size_t)n * IN + j * (IN / SPLIT));
#pragma unroll
    for (int k4 = 0; k4 < PIN4; ++k4) {
      f4v xv = __builtin_nontemporal_load(&x4[k4]);
      const int kb = j * (IN / SPLIT) + 4 * k4;
#pragma unroll
      for (int q = 0; q < OUT; ++q) {
        acc[q] += xv[0] * Ws[(kb + 0) * OUT + q];
        acc[q] += xv[1] * Ws[(kb + 1) * OUT + q];
        acc[q] += xv[2] * Ws[(kb + 2) * OUT + q];
        acc[q] += xv[3] * Ws[(kb + 3) * OUT + q];
      }
    }
#pragma unroll
    for (int o = 1; o < SPLIT; o <<= 1) {
#pragma unroll
      for (int q = 0; q < OUT; ++q) acc[q] += __shfl_xor(acc[q], o);
    }
    if (j < OUT / 4) {
      h4v v;
      v[0] = (_Float16)acc[4 * j + 0];
      v[1] = (_Float16)acc[4 * j + 1];
      v[2] = (_Float16)acc[4 * j + 2];
      v[3] = (_Float16)acc[4 * j + 3];
      reinterpret_cast<h4v*>(hout + (size_t)n * OUT)[j] = v;
    }
    if (j < 2) {
      float dd = 0.f;
#pragma unroll
      for (int c = 0; c < 8; ++c) dd += acc[j * 8 + c] * Ad[j * 8 + c];
      ad_[n * 2 + j] = dd;
    }
  }
}

// A2a: per-bucket exclusive scan over blocks (grid = NBKT, block = NB_P threads).
__global__ void k_bscan1(const int* __restrict__ cnt, int* __restrict__ off,
                         int* __restrict__ colTotal) {
  __shared__ int sh[NB_P];
  const int t = threadIdx.x;
  const int b = blockIdx.x;
  int v = cnt[b * NB_P + t];
  sh[t] = v;
  __syncthreads();
  for (int o = 1; o < NB_P; o <<= 1) {
    int u = (t >= o) ? sh[t - o] : 0;
    __syncthreads();
    sh[t] += u;
    __syncthreads();
  }
  off[b * NB_P + t] = sh[t] - v;
  if (t == NB_P - 1) colTotal[b] = sh[t];
}

// A2b: exclusive scan of bucket totals -> bucketBase[NBKT+1].
__global__ void k_bscan2(const int* __restrict__ colTotal, int* __restrict__ bucketBase) {
  __shared__ int sh[NBKT];
  const int t = threadIdx.x;
  int v = colTotal[t];
  sh[t] = v;
  __syncthreads();
  for (int o = 1; o < NBKT; o <<= 1) {
    int u = (t >= o) ? sh[t - o] : 0;
    __syncthreads();
    sh[t] += u;
    __syncthreads();
  }
  bucketBase[t] = sh[t] - v;
  if (t == NBKT - 1) bucketBase[NBKT] = sh[t];
}

// B: per-bucket counting sort; gather via binary search (pass 1 only — pk
// register-cached for pass 2); LDS staging; coalesced colIdx write.
__global__ void k_bsort(const int* __restrict__ epkPriv, const int* __restrict__ off,
                        const int* __restrict__ loffG, const int* __restrict__ bucketBase,
                        int* __restrict__ rowStart, int* __restrict__ colIdx,
                        int N, int R, int E, int CHP) {
  __shared__ int offRow[NB_P];
  __shared__ int loffCol[NB_P];
  __shared__ int sc[256];
  __shared__ int stg[STG_CAP];
  const int b = (blockIdx.x & (NGRP - 1)) * (NBKT / NGRP) + (blockIdx.x >> 3);
  const int lo = bucketBase[b], hi = bucketBase[b + 1];
  const int cntB = hi - lo;
  const int nodeLo = b * R;
  const int nN = min(R, N - nodeLo);
  const int t = threadIdx.x;
  for (int i = t; i < NB_P; i += SORT_T) {
    offRow[i] = off[b * NB_P + i];
    loffCol[i] = loffG[i * NBKT + b];
  }
  if (t < 256) sc[t] = 0;
  __syncthreads();
  auto fetch = [&](int i) -> int {
    int loQ = 0, hiQ = NB_P;
#pragma unroll
    for (int it = 0; it < 10; ++it) {
      int mid = (loQ + hiQ) >> 1;
      if (offRow[mid] <= i) loQ = mid; else hiQ = mid;
    }
    return epkPriv[(size_t)loQ * CHP + loffCol[loQ] + (i - offRow[loQ])];
  };
  // pass 1: histogram, register-caching pk (static indices -> VGPRs)
  int pkc[RB];
#pragma unroll
  for (int r = 0; r < RB; ++r) {
    const int i = t + r * SORT_T;
    int pk = -1;
    if (i < cntB) {
      pk = fetch(i);
      atomicAdd(&sc[pk >> 17], 1);
    }
    pkc[r] = pk;
  }
  for (int i = t + RB * SORT_T; i < cntB; i += SORT_T) {
    int pk = fetch(i);
    atomicAdd(&sc[pk >> 17], 1);
  }
  __syncthreads();
  int own = (t < 256) ? sc[t] : 0;
  for (int o = 1; o < 256; o <<= 1) {
    int u = (t < 256 && t >= o) ? sc[t - o] : 0;
    __syncthreads();
    if (t < 256) sc[t] += u;
    __syncthreads();
  }
  if (t < nN) rowStart[nodeLo + t] = lo + sc[t] - own;
  if (b == NBKT - 1 && t == 0) rowStart[N] = E;
  if (t < 256) sc[t] -= own;
  __syncthreads();
  // pass 2: placement from cached pk
  if (cntB <= STG_CAP) {
#pragma unroll
    for (int r = 0; r < RB; ++r) {
      const int i = t + r * SORT_T;
      if (i < cntB) {
        int pk = pkc[r];
        int pos = atomicAdd(&sc[pk >> 17], 1);
        stg[pos] = pk & 0x1FFFF;
      }
    }
    for (int i = t + RB * SORT_T; i < cntB; i += SORT_T) {
      int pk = fetch(i);
      int pos = atomicAdd(&sc[pk >> 17], 1);
      stg[pos] = pk & 0x1FFFF;
    }
    __syncthreads();
    for (int i = t; i < cntB; i += SORT_T) colIdx[lo + i] = stg[i];  // coalesced
  } else {
#pragma unroll
    for (int r = 0; r < RB; ++r) {
      const int i = t + r * SORT_T;
      if (i < cntB) {
        int pk = pkc[r];
        int pos = lo + atomicAdd(&sc[pk >> 17], 1);
        colIdx[pos] = pk & 0x1FFFF;
      }
    }
    for (int i = t + RB * SORT_T; i < cntB; i += SORT_T) {
      int pk = fetch(i);
      int pos = lo + atomicAdd(&sc[pk >> 17], 1);
      colIdx[pos] = pk & 0x1FFFF;
    }
  }
}

// ================= edge layer 1 + fused node transform 2 =================
// L=2 x 16B h1 gathers, S=4, masked chunks. Depth-2 pipeline: colIdx 2 ahead,
// h-gathers 1 chunk ahead. as recomputed in-register (1 line/edge).

__global__ void k_edge12(const int* __restrict__ rowStart, const int* __restrict__ colIdx,
                         const _Float16* __restrict__ h1, const float* __restrict__ as1w,
                         const float* __restrict__ ad_, const float* __restrict__ b1,
                         const float* __restrict__ W2, const float* __restrict__ as2w,
                         const float* __restrict__ ad2w, Rec2* __restrict__ r2,
                         float* __restrict__ ad2, int N, int R8) {
  constexpr int L = 2, S = 4, LS = 8, NPB = TB / LS;
  __shared__ float Ws2[128], A1s[16], A2s[8], A2d[8], B1s[16];
  if (threadIdx.x < 128) Ws2[threadIdx.x] = W2[threadIdx.x];
  if (threadIdx.x < 16) {
    A1s[threadIdx.x] = as1w[threadIdx.x];
    B1s[threadIdx.x] = b1[threadIdx.x];
  }
  if (threadIdx.x < 8) {
    A2s[threadIdx.x] = as2w[threadIdx.x];
    A2d[threadIdx.x] = ad2w[threadIdx.x];
  }
  __syncthreads();
  const int g = blockIdx.x & (NGRP - 1);
  const int lb = blockIdx.x / NGRP;
  const int lane = threadIdx.x % LS;
  const int sub = lane >> 1;
  const int j = lane & 1;
  const int n = g * R8 + lb * NPB + threadIdx.x / LS;
  const int nEnd = min((g + 1) * R8, N);
  if (n >= nEnd) return;
  const float adv = ad_[n * 2 + j];
  float aw[8];
#pragma unroll
  for (int c = 0; c < 8; ++c) aw[c] = A1s[j * 8 + c];
  const int start = rowStart[n];
  const int end = rowStart[n + 1];
  float s = 0.f, acc[8];
#pragma unroll
  for (int q = 0; q < 8; ++q) acc[q] = 0.f;
  if (sub == 0) {  // self-loop
    h8v a0 = reinterpret_cast<const h8v*>(h1 + (size_t)n * 16)[j];
    float e = 0.f;
#pragma unroll
    for (int c = 0; c < 8; ++c) e += (float)a0[c] * aw[c];
    float p = __expf(leaky(e + adv));
    s = p;
#pragma unroll
    for (int q = 0; q < 8; ++q) acc[q] = p * (float)a0[q];
  }
  const h8v* hrows = reinterpret_cast<const h8v*>(h1);
  const int base = start & ~3;
  const int nch = (end - base + 3) >> 2;
  const int nmine = (nch > sub) ? ((nch - sub + S - 1) / S) : 0;
  int ti = sub;
  i4v cv0, cv1;
  h8v g0, g1, g2, g3;
  if (nmine >= 1) cv0 = *reinterpret_cast<const i4v*>(colIdx + base + 4 * sub);
  if (nmine >= 2) cv1 = *reinterpret_cast<const i4v*>(colIdx + base + 4 * (sub + S));
  if (nmine >= 1) {
    const int i0 = base + 4 * ti;
    g0 = hrows[(size_t)(((i0 + 0 >= start) && (i0 + 0 < end)) ? cv0[0] : n) * 2 + j];
    g1 = hrows[(size_t)(((i0 + 1 >= start) && (i0 + 1 < end)) ? cv0[1] : n) * 2 + j];
    g2 = hrows[(size_t)(((i0 + 2 >= start) && (i0 + 2 < end)) ? cv0[2] : n) * 2 + j];
    g3 = hrows[(size_t)(((i0 + 3 >= start) && (i0 + 3 < end)) ? cv0[3] : n) * 2 + j];
  }
  for (int m = 0; m < nmine; ++m) {
    const int i0 = base + 4 * ti;
    i4v cv2 = cv1;
    if (m + 2 < nmine) cv2 = *reinterpret_cast<const i4v*>(colIdx + base + 4 * (ti + 2 * S));
    h8v n0 = g0, n1 = g1, n2 = g2, n3 = g3;
    if (m + 1 < nmine) {  // issue next chunk's gathers before computing current
      const int ni0 = base + 4 * (ti + S);
      n0 = hrows[(size_t)(((ni0 + 0 >= start) && (ni0 + 0 < end)) ? cv1[0] : n) * 2 + j];
      n1 = hrows[(size_t)(((ni0 + 1 >= start) && (ni0 + 1 < end)) ? cv1[1] : n) * 2 + j];
      n2 = hrows[(size_t)(((ni0 + 2 >= start) && (ni0 + 2 < end)) ? cv1[2] : n) * 2 + j];
      n3 = hrows[(size_t)(((ni0 + 3 >= start) && (ni0 + 3 < end)) ? cv1[3] : n) * 2 + j];
    }
#pragma unroll
    for (int k = 0; k < 4; ++k) {
      const bool ok = (i0 + k >= start) && (i0 + k < end);
      h8v hv = (k == 0) ? g0 : (k == 1) ? g1 : (k == 2) ? g2 : g3;
      float e = 0.f;
#pragma unroll
      for (int c = 0; c < 8; ++c) e += (float)hv[c] * aw[c];
      float p = ok ? __expf(leaky(e + adv)) : 0.f;
      s += p;
#pragma unroll
      for (int q = 0; q < 8; ++q) acc[q] += p * (float)hv[q];
    }
    cv0 = cv1; cv1 = cv2;
    g0 = n0; g1 = n1; g2 = n2; g3 = n3;
    ti += S;
  }
#pragma unroll
  for (int off = L; off < LS; off <<= 1) {
    s += __shfl_xor(s, off);
#pragma unroll
    for (int q = 0; q < 8; ++q) acc[q] += __shfl_xor(acc[q], off);
  }
  if (sub == 0) {
    float inv = 1.f / (s + 1e-16f);
    float o1v[8];
#pragma unroll
    for (int q = 0; q < 8; ++q) o1v[q] = fmaxf(acc[q] * inv + B1s[j * 8 + q], 0.f);
    float h2p[8];
#pragma unroll
    for (int q = 0; q < 8; ++q) {
      float tacc = 0.f;
#pragma unroll
      for (int c = 0; c < 8; ++c) tacc += o1v[c] * Ws2[(j * 8 + c) * 8 + q];
      h2p[q] = tacc;
    }
    float h2f[8];
#pragma unroll
    for (int q = 0; q < 8; ++q) h2f[q] = h2p[q] + __shfl_xor(h2p[q], 1);
    h4v v;
#pragma unroll
    for (int q = 0; q < 4; ++q) v[q] = (_Float16)h2f[j * 4 + q];
    reinterpret_cast<h4v*>(r2[n].h)[j] = v;
    float ss = 0.f, dd = 0.f;
#pragma unroll
    for (int c = 0; c < 4; ++c) {
      ss += h2f[j * 4 + c] * A2s[j * 4 + c];
      dd += h2f[j * 4 + c] * A2d[j * 4 + c];
    }
    r2[n].as[j] = ss;
    ad2[n * 2 + j] = dd;
  }
}

// ================= edge layer 2 + fused node transform 3 =================
// Depth-2 pipelined Rec2 gathers (h + as from one 32B record).

__global__ void k_edge23(const int* __restrict__ rowStart, const int* __restrict__ colIdx,
                         const Rec2* __restrict__ r2, const float* __restrict__ ad_,
                         const float* __restrict__ b2, const float* __restrict__ W3,
                         const float* __restrict__ as3w, const float* __restrict__ ad3w,
                         Rec3* __restrict__ r3, float* __restrict__ ad3, int N, int R8) {
  constexpr int L = 2, S = 4, LS = 8, NPB = TB / LS;
  __shared__ float Ws3[32], A3s[4], A3d[4], B2s[8];
  if (threadIdx.x < 32) Ws3[threadIdx.x] = W3[threadIdx.x];
  if (threadIdx.x < 4) {
    A3s[threadIdx.x] = as3w[threadIdx.x];
    A3d[threadIdx.x] = ad3w[threadIdx.x];
  }
  if (threadIdx.x < 8) B2s[threadIdx.x] = b2[threadIdx.x];
  __syncthreads();
  const int g = blockIdx.x & (NGRP - 1);
  const int lb = blockIdx.x / NGRP;
  const int lane = threadIdx.x % LS;
  const int sub = lane >> 1;
  const int j = lane & 1;
  const int n = g * R8 + lb * NPB + threadIdx.x / LS;
  const int nEnd = min((g + 1) * R8, N);
  if (n >= nEnd) return;
  const float adv = ad_[n * 2 + j];
  const int start = rowStart[n];
  const int end = rowStart[n + 1];
  float s = 0.f, acc[4];
#pragma unroll
  for (int q = 0; q < 4; ++q) acc[q] = 0.f;
  if (sub == 0) {
    float p = __expf(leaky(r2[n].as[j] + adv));
    h4v a0 = reinterpret_cast<const h4v*>(r2[n].h)[j];
    s = p;
#pragma unroll
    for (int q = 0; q < 4; ++q) acc[q] = p * (float)a0[q];
  }
  const int base = start & ~3;
  const int nch = (end - base + 3) >> 2;
  const int nmine = (nch > sub) ? ((nch - sub + S - 1) / S) : 0;
  int ti = sub;
  i4v cv0, cv1;
  h4v g0, g1, g2, g3;
  float e0, e1, e2, e3;
  auto issue = [&](const i4v& cv, int i0, h4v& o0, h4v& o1, h4v& o2, h4v& o3,
                   float& f0, float& f1, float& f2, float& f3) {
    int s0 = ((i0 + 0 >= start) && (i0 + 0 < end)) ? cv[0] : n;
    int s1 = ((i0 + 1 >= start) && (i0 + 1 < end)) ? cv[1] : n;
    int s2 = ((i0 + 2 >= start) && (i0 + 2 < end)) ? cv[2] : n;
    int s3 = ((i0 + 3 >= start) && (i0 + 3 < end)) ? cv[3] : n;
    o0 = reinterpret_cast<const h4v*>(r2[s0].h)[j]; f0 = r2[s0].as[j];
    o1 = reinterpret_cast<const h4v*>(r2[s1].h)[j]; f1 = r2[s1].as[j];
    o2 = reinterpret_cast<const h4v*>(r2[s2].h)[j]; f2 = r2[s2].as[j];
    o3 = reinterpret_cast<const h4v*>(r2[s3].h)[j]; f3 = r2[s3].as[j];
  };
  if (nmine >= 1) cv0 = *reinterpret_cast<const i4v*>(colIdx + base + 4 * sub);
  if (nmine >= 2) cv1 = *reinterpret_cast<const i4v*>(colIdx + base + 4 * (sub + S));
  if (nmine >= 1) issue(cv0, base + 4 * ti, g0, g1, g2, g3, e0, e1, e2, e3);
  for (int m = 0; m < nmine; ++m) {
    const int i0 = base + 4 * ti;
    i4v cv2 = cv1;
    if (m + 2 < nmine) cv2 = *reinterpret_cast<const i4v*>(colIdx + base + 4 * (ti + 2 * S));
    h4v n0 = g0, n1 = g1, n2 = g2, n3 = g3;
    float f0 = e0, f1 = e1, f2 = e2, f3 = e3;
    if (m + 1 < nmine) issue(cv1, base + 4 * (ti + S), n0, n1, n2, n3, f0, f1, f2, f3);
#pragma unroll
    for (int k = 0; k < 4; ++k) {
      const bool ok = (i0 + k >= start) && (i0 + k < end);
      h4v hv = (k == 0) ? g0 : (k == 1) ? g1 : (k == 2) ? g2 : g3;
      float e = (k == 0) ? e0 : (k == 1) ? e1 : (k == 2) ? e2 : e3;
      float p = ok ? __expf(leaky(e + adv)) : 0.f;
      s += p;
#pragma unroll
      for (int q = 0; q < 4; ++q) acc[q] += p * (float)hv[q];
    }
    cv0 = cv1; cv1 = cv2;
    g0 = n0; g1 = n1; g2 = n2; g3 = n3;
    e0 = f0; e1 = f1; e2 = f2; e3 = f3;
    ti += S;
  }
#pragma unroll
  for (int off = L; off < LS; off <<= 1) {
    s += __shfl_xor(s, off);
#pragma unroll
    for (int q = 0; q < 4; ++q) acc[q] += __shfl_xor(acc[q], off);
  }
  if (sub == 0) {
    float inv = 1.f / (s + 1e-16f);
    float o2v[4];
#pragma unroll
    for (int q = 0; q < 4; ++q) o2v[q] = fmaxf(acc[q] * inv + B2s[j * 4 + q], 0.f);
    float h3p[4];
#pragma unroll
    for (int q = 0; q < 4; ++q) {
      float tacc = 0.f;
#pragma unroll
      for (int c = 0; c < 4; ++c) tacc += o2v[c] * Ws3[(j * 4 + c) * 4 + q];
      h3p[q] = tacc;
    }
    float h3f[4];
#pragma unroll
    for (int q = 0; q < 4; ++q) h3f[q] = h3p[q] + __shfl_xor(h3p[q], 1);
    if (j == 0) {
      Rec3 rec;
#pragma unroll
      for (int q = 0; q < 4; ++q) rec.h[q] = (_Float16)h3f[q];
      float ss = 0.f, dd = 0.f;
#pragma unroll
      for (int c = 0; c < 4; ++c) {
        ss += h3f[c] * A3s[c];
        dd += h3f[c] * A3d[c];
      }
      rec.as = ss;
      rec.pad = 0.f;
      r3[n] = rec;
      ad3[n] = dd;
    }
  }
}

// ================= edge layer 3 + fused classifier; S=8, depth-2 pipeline =================

__global__ void k_edge3(const int* __restrict__ rowStart, const int* __restrict__ colIdx,
                        const Rec3* __restrict__ r3, const float* __restrict__ ad_,
                        const float* __restrict__ b3, const float* __restrict__ Wc,
                        const float* __restrict__ bc, float* __restrict__ out,
                        int N, int R8) {
  constexpr int S = 8;
  constexpr int NPB = TB / S;
  const int g = blockIdx.x & (NGRP - 1);
  const int lb = blockIdx.x / NGRP;
  const int sub = threadIdx.x % S;
  const int n = g * R8 + lb * NPB + threadIdx.x / S;
  const int nEnd = min((g + 1) * R8, N);
  if (n >= nEnd) return;
  const float adv = ad_[n];
  const int start = rowStart[n];
  const int end = rowStart[n + 1];
  float s = 0.f, acc0 = 0.f, acc1 = 0.f, acc2 = 0.f, acc3 = 0.f;
  if (sub == 0) {
    Rec3 rec = r3[n];
    float p = __expf(leaky(rec.as + adv));
    s = p;
    acc0 = p * (float)rec.h[0];
    acc1 = p * (float)rec.h[1];
    acc2 = p * (float)rec.h[2];
    acc3 = p * (float)rec.h[3];
  }
  const int base = start & ~3;
  const int nch = (end - base + 3) >> 2;
  const int nmine = (nch > sub) ? ((nch - sub + S - 1) / S) : 0;
  int ti = sub;
  i4v cv0, cv1;
  Rec3 g0, g1, g2, g3;
  auto issue = [&](const i4v& cv, int i0, Rec3& o0, Rec3& o1, Rec3& o2, Rec3& o3) {
    o0 = r3[((i0 + 0 >= start) && (i0 + 0 < end)) ? cv[0] : n];
    o1 = r3[((i0 + 1 >= start) && (i0 + 1 < end)) ? cv[1] : n];
    o2 = r3[((i0 + 2 >= start) && (i0 + 2 < end)) ? cv[2] : n];
    o3 = r3[((i0 + 3 >= start) && (i0 + 3 < end)) ? cv[3] : n];
  };
  if (nmine >= 1) cv0 = *reinterpret_cast<const i4v*>(colIdx + base + 4 * sub);
  if (nmine >= 2) cv1 = *reinterpret_cast<const i4v*>(colIdx + base + 4 * (sub + S));
  if (nmine >= 1) issue(cv0, base + 4 * ti, g0, g1, g2, g3);
  for (int m = 0; m < nmine; ++m) {
    const int i0 = base + 4 * ti;
    i4v cv2 = cv1;
    if (m + 2 < nmine) cv2 = *reinterpret_cast<const i4v*>(colIdx + base + 4 * (ti + 2 * S));
    Rec3 n0 = g0, n1 = g1, n2 = g2, n3 = g3;
    if (m + 1 < nmine) issue(cv1, base + 4 * (ti + S), n0, n1, n2, n3);
#pragma unroll
    for (int k = 0; k < 4; ++k) {
      const bool ok = (i0 + k >= start) && (i0 + k < end);
      Rec3 rec = (k == 0) ? g0 : (k == 1) ? g1 : (k == 2) ? g2 : g3;
      float p = ok ? __expf(leaky(rec.as + adv)) : 0.f;
      s += p;
      acc0 += p * (float)rec.h[0];
      acc1 += p * (float)rec.h[1];
      acc2 += p * (float)rec.h[2];
      acc3 += p * (float)rec.h[3];
    }
    cv0 = cv1; cv1 = cv2;
    g0 = n0; g1 = n1; g2 = n2; g3 = n3;
    ti += S;
  }
#pragma unroll
  for (int off = 1; off < S; off <<= 1) {
    s += __shfl_xor(s, off);
    acc0 += __shfl_xor(acc0, off);
    acc1 += __shfl_xor(acc1, off);
    acc2 += __shfl_xor(acc2, off);
    acc3 += __shfl_xor(acc3, off);
  }
  if (sub == 0) {
    float inv = 1.f / (s + 1e-16f);
    float o0 = acc0 * inv + b3[0];
    float o1 = acc1 * inv + b3[1];
    float o2 = acc2 * inv + b3[2];
    float o3 = acc3 * inv + b3[3];
    float2 r;
    r.x = o0 * Wc[0] + o1 * Wc[2] + o2 * Wc[4] + o3 * Wc[6] + bc[0];
    r.y = o0 * Wc[1] + o1 * Wc[3] + o2 * Wc[5] + o3 * Wc[7] + bc[1];
    reinterpret_cast<float2*>(out)[n] = r;
  }
}

// ================= launch =================

extern "C" void kernel_launch(void* const* d_in, const int* in_sizes, int n_in,
                              void* d_out, int out_size, void* d_ws, size_t ws_size,
                              hipStream_t stream) {
  const float* x    = (const float*)d_in[0];
  const int*   ei   = (const int*)d_in[1];
  const float* W1   = (const float*)d_in[2];
  const float* as1w = (const float*)d_in[3];
  const float* ad1w = (const float*)d_in[4];
  const float* b1   = (const float*)d_in[5];
  const float* W2   = (const float*)d_in[6];
  const float* as2w = (const float*)d_in[7];
  const float* ad2w = (const float*)d_in[8];
  const float* b2   = (const float*)d_in[9];
  const float* W3   = (const float*)d_in[10];
  const float* as3w = (const float*)d_in[11];
  const float* ad3w = (const float*)d_in[12];
  const float* b3   = (const float*)d_in[13];
  const float* Wc   = (const float*)d_in[14];
  const float* bc   = (const float*)d_in[15];
  float* out = (float*)d_out;

  const int N = in_sizes[0] / 128;
  const int E = in_sizes[1] / 2;
  const int* srcA = ei;
  const int* dstA = ei + E;

  char* p = (char*)d_ws;
  auto alloc = [&](size_t bytes) -> void* {
    void* r = (void*)p;
    p += (bytes + 255) & ~(size_t)255;
    return r;
  };
  const int E4  = E >> 2;
  const int CH4 = (E4 + NB_P - 1) / NB_P;
  const int CHP = CH4 * 4 + 8;

  int* cnt        = (int*)alloc((size_t)NBKT * NB_P * 4);
  int* off        = (int*)alloc((size_t)NBKT * NB_P * 4);
  int* loffG      = (int*)alloc((size_t)NB_P * NBKT * 4);
  int* colTotal   = (int*)alloc(NBKT * 4);
  int* bucketBase = (int*)alloc((NBKT + 1) * 4);
  int* rowStart   = (int*)alloc((size_t)(N + 1) * 4);
  int* epkPriv    = (int*)alloc((size_t)NB_P * CHP * 4);
  int* colIdx     = (int*)alloc((size_t)E * 4 + 256);
  _Float16* h1 = (_Float16*)alloc((size_t)N * 16 * 2);
  float* ad1 = (float*)alloc((size_t)N * 2 * 4);
  Rec2* r2   = (Rec2*)alloc((size_t)N * sizeof(Rec2));
  float* ad2 = (float*)alloc((size_t)N * 2 * 4);
  Rec3* r3   = (Rec3*)alloc((size_t)N * sizeof(Rec3));
  float* ad3 = (float*)alloc((size_t)N * 4);

  const int R   = (N + NBKT - 1) / NBKT;                       // nodes per bucket (196)
  const unsigned M = (unsigned)(((1ULL << 32) + R - 1) / R);   // exact /R via __umulhi
  const int R8  = R * (NBKT / NGRP);                           // nodes per XCD (12544)

  const int nb1 = (N + (TB / 4) - 1) / (TB / 4);   // node1 blocks (SPLIT=4)
  const int ge8 = NGRP * ((R8 + (TB / 8) - 1) / (TB / 8));  // 32 nodes/block

  // single-pass CSR scatter + node1 overlapped in the first dispatch
  k_scatter_node1<<<NB_P + nb1, TB, 0, stream>>>(srcA, dstA, cnt, loffG, epkPriv,
                                                 E4, E, M, R, CH4, CHP,
                                                 x, W1, as1w, ad1w, h1, ad1, N);
  k_bscan1<<<NBKT, NB_P, 0, stream>>>(cnt, off, colTotal);
  k_bscan2<<<1, NBKT, 0, stream>>>(colTotal, bucketBase);
  k_bsort<<<NBKT, SORT_T, 0, stream>>>(epkPriv, off, loffG, bucketBase, rowStart,
                                       colIdx, N, R, E, CHP);

  k_edge12<<<ge8, TB, 0, stream>>>(rowStart, colIdx, h1, as1w, ad1, b1, W2, as2w, ad2w,
                                   r2, ad2, N, R8);
  k_edge23<<<ge8, TB, 0, stream>>>(rowStart, colIdx, r2, ad2, b2, W3, as3w, ad3w,
                                   r3, ad3, N, R8);
  k_edge3<<<ge8, TB, 0, stream>>>(rowStart, colIdx, r3, ad3, b3, Wc, bc, out, N, R8);
}

// Round 21
// 148.035 us; speedup vs baseline: 1.0300x; 1.0300x over previous
//
#include <hip/hip_runtime.h>

#define TB 256
#define NGRP 8            // XCDs on MI355X
#define NB_P 1024         // partition blocks
#define TBP 256           // partition block threads
#define NBKT 256          // dst-range buckets (32 per XCD)
#define SORT_T 1024
#define STG_CAP 13312     // LDS staging entries in k_bsort
#define STG2_CAP 3200     // LDS staging entries in k_scatter
#define RCAP 4            // register-cached int4 chunks per thread in scatter
#define RB 14             // register-cached pk entries per thread in bsort

typedef int      i4v __attribute__((ext_vector_type(4)));
typedef float    f4v __attribute__((ext_vector_type(4)));
typedef _Float16 h4v __attribute__((ext_vector_type(4)));
typedef _Float16 h8v __attribute__((ext_vector_type(8)));

// Packed gather records: one cache line fetch per edge.
struct __align__(16) Rec2 { _Float16 h[8]; float as[2]; float pad[2]; };  // 32 B
struct __align__(16) Rec3 { _Float16 h[4]; float as; float pad; };        // 16 B

static __device__ __forceinline__ float leaky(float x) {
  return x > 0.f ? x : 0.2f * x;
}

// ========== fused single-pass scatter + node1 (champion form) ==========
// Blocks [0,NB_P): edge-chunk counting-sort into private region with per-wave
// bucket cursors; LDS staging + coalesced flush. Blocks [NB_P,...): x@W1.

__global__ void __launch_bounds__(TB)
k_scatter_node1(const int* __restrict__ srcA, const int* __restrict__ dstA,
                int* __restrict__ cnt, int* __restrict__ loffG,
                int* __restrict__ epkPriv, int E4, int E, unsigned M, int R,
                int CH4, int CHP,
                const float* __restrict__ xin, const float* __restrict__ W1,
                const float* __restrict__ a_src, const float* __restrict__ a_dst,
                _Float16* __restrict__ hout, float* __restrict__ ad_, int N) {
  __shared__ __align__(16) char smem[18960];
  const int t = threadIdx.x;
  if (blockIdx.x < NB_P) {
    const int kblk = blockIdx.x;
    int* lc   = (int*)smem;                 // 4*NBKT: sub-hists, then per-wave cursors
    int* loff = (int*)(smem + 4096);        // NBKT+1
    int* stg  = (int*)(smem + 5136);        // STG2_CAP
    for (int i = t; i < 4 * NBKT; i += TBP) lc[i] = 0;
    __syncthreads();
    int* lcw = lc + (t >> 6) * NBKT;
    const int bstart = kblk * CH4;
    const int bend = min(E4, bstart + CH4);
    const i4v* d4 = reinterpret_cast<const i4v*>(dstA);
    const i4v* s4 = reinterpret_cast<const i4v*>(srcA);
    i4v dr[RCAP], sr[RCAP];
    // pass 1: load chunk into registers + per-wave histogram
    int it1 = 0;
    for (int i = bstart + t; i < bend; i += TBP, ++it1) {
      i4v d = __builtin_nontemporal_load(&d4[i]);
      i4v sv = __builtin_nontemporal_load(&s4[i]);
      if (it1 < RCAP) { dr[it1] = d; sr[it1] = sv; }
#pragma unroll
      for (int k = 0; k < 4; ++k) atomicAdd(&lcw[__umulhi((unsigned)d[k], M)], 1);
    }
    if (kblk == NB_P - 1) {
      for (int i = E4 * 4 + t; i < E; i += TBP)
        atomicAdd(&lcw[__umulhi((unsigned)dstA[i], M)], 1);
    }
    __syncthreads();
    // reduce sub-hists + exclusive scan -> bucket layout; emit cnt, loffG
    int c0 = 0, c1 = 0, c2 = 0, c3 = 0, c = 0;
    if (t < NBKT) {
      c0 = lc[t]; c1 = lc[NBKT + t]; c2 = lc[2 * NBKT + t]; c3 = lc[3 * NBKT + t];
      c = c0 + c1 + c2 + c3;
      loff[t] = c;
    }
    __syncthreads();
    for (int o = 1; o < NBKT; o <<= 1) {
      int u = (t < NBKT && t >= o) ? loff[t - o] : 0;
      __syncthreads();
      if (t < NBKT) loff[t] += u;
      __syncthreads();
    }
    int excl = 0;
    if (t < NBKT) excl = loff[t] - c;
    __syncthreads();
    if (t < NBKT) {
      cnt[t * NB_P + kblk] = c;          // [bucket][block] for bscan1
      loffG[kblk * NBKT + t] = excl;     // block-major local offsets
      loff[t] = excl;
      if (t == NBKT - 1) loff[NBKT] = excl + c;
      // per-wave cursor bases (overwrite sub-hists in place)
      lc[t] = excl;
      lc[NBKT + t] = excl + c0;
      lc[2 * NBKT + t] = excl + c0 + c1;
      lc[3 * NBKT + t] = excl + c0 + c1 + c2;
    }
    __syncthreads();
    // pass 2: scatter packed edges into LDS by bucket, per-wave cursors
    int it2 = 0;
    for (int i = bstart + t; i < bend; i += TBP, ++it2) {
      i4v d = (it2 < RCAP) ? dr[it2] : d4[i];
      i4v sv = (it2 < RCAP) ? sr[it2] : s4[i];
#pragma unroll
      for (int k = 0; k < 4; ++k) {
        int dd = d[k];
        int b = __umulhi((unsigned)dd, M);
        int pos = atomicAdd(&lcw[b], 1);
        stg[pos] = ((dd - b * R) << 17) | sv[k];
      }
    }
    if (kblk == NB_P - 1) {
      for (int i = E4 * 4 + t; i < E; i += TBP) {
        int dd = dstA[i];
        int b = __umulhi((unsigned)dd, M);
        int pos = atomicAdd(&lcw[b], 1);
        stg[pos] = ((dd - b * R) << 17) | srcA[i];
      }
    }
    __syncthreads();
    // linear coalesced flush to private region
    const int total = loff[NBKT];
    int* dst = epkPriv + (size_t)kblk * CHP;
    for (int i = t; i < total; i += TBP) dst[i] = stg[i];
  } else {
    // ---- node transform layer 1: IN=128, H=2, C=8, SPLIT=4 ----
    constexpr int IN = 128, OUT = 16, SPLIT = 4, NPB = TB / SPLIT, PIN4 = IN / SPLIT / 4;
    float* Ws = (float*)smem;
    float* Ad = (float*)(smem + 8192);
    const int bid = blockIdx.x - NB_P;
    for (int i = t; i < IN * OUT; i += TB) Ws[i] = W1[i];
    if (t < OUT) Ad[t] = a_dst[t];
    __syncthreads();
    const int j = t & (SPLIT - 1);
    const int n = bid * NPB + t / SPLIT;
    if (n >= N) return;
    float acc[OUT];
#pragma unroll
    for (int q = 0; q < OUT; ++q) acc[q] = 0.f;
    const f4v* x4 = reinterpret_cast<const f4v*>(xin + (size_t)n * IN + j * (IN / SPLIT));
#pragma unroll
    for (int k4 = 0; k4 < PIN4; ++k4) {
      f4v xv = __builtin_nontemporal_load(&x4[k4]);
      const int kb = j * (IN / SPLIT) + 4 * k4;
#pragma unroll
      for (int q = 0; q < OUT; ++q) {
        acc[q] += xv[0] * Ws[(kb + 0) * OUT + q];
        acc[q] += xv[1] * Ws[(kb + 1) * OUT + q];
        acc[q] += xv[2] * Ws[(kb + 2) * OUT + q];
        acc[q] += xv[3] * Ws[(kb + 3) * OUT + q];
      }
    }
#pragma unroll
    for (int o = 1; o < SPLIT; o <<= 1) {
#pragma unroll
      for (int q = 0; q < OUT; ++q) acc[q] += __shfl_xor(acc[q], o);
    }
    if (j < OUT / 4) {
      h4v v;
      v[0] = (_Float16)acc[4 * j + 0];
      v[1] = (_Float16)acc[4 * j + 1];
      v[2] = (_Float16)acc[4 * j + 2];
      v[3] = (_Float16)acc[4 * j + 3];
      reinterpret_cast<h4v*>(hout + (size_t)n * OUT)[j] = v;
    }
    if (j < 2) {
      float dd = 0.f;
#pragma unroll
      for (int c = 0; c < 8; ++c) dd += acc[j * 8 + c] * Ad[j * 8 + c];
      ad_[n * 2 + j] = dd;
    }
  }
}

// A2a: per-bucket exclusive scan over blocks (grid = NBKT, block = NB_P threads).
__global__ void k_bscan1(const int* __restrict__ cnt, int* __restrict__ off,
                         int* __restrict__ colTotal) {
  __shared__ int sh[NB_P];
  const int t = threadIdx.x;
  const int b = blockIdx.x;
  int v = cnt[b * NB_P + t];
  sh[t] = v;
  __syncthreads();
  for (int o = 1; o < NB_P; o <<= 1) {
    int u = (t >= o) ? sh[t - o] : 0;
    __syncthreads();
    sh[t] += u;
    __syncthreads();
  }
  off[b * NB_P + t] = sh[t] - v;
  if (t == NB_P - 1) colTotal[b] = sh[t];
}

// A2b: exclusive scan of bucket totals -> bucketBase[NBKT+1].
__global__ void k_bscan2(const int* __restrict__ colTotal, int* __restrict__ bucketBase) {
  __shared__ int sh[NBKT];
  const int t = threadIdx.x;
  int v = colTotal[t];
  sh[t] = v;
  __syncthreads();
  for (int o = 1; o < NBKT; o <<= 1) {
    int u = (t >= o) ? sh[t - o] : 0;
    __syncthreads();
    sh[t] += u;
    __syncthreads();
  }
  bucketBase[t] = sh[t] - v;
  if (t == NBKT - 1) bucketBase[NBKT] = sh[t];
}

// B: per-bucket counting sort; gather from block-private runs via binary
// search (pass 1 only — pk register-cached for pass 2); LDS staging;
// coalesced colIdx write (fallback if bucket > cap).
__global__ void k_bsort(const int* __restrict__ epkPriv, const int* __restrict__ off,
                        const int* __restrict__ loffG, const int* __restrict__ bucketBase,
                        int* __restrict__ rowStart, int* __restrict__ colIdx,
                        int N, int R, int E, int CHP) {
  __shared__ int offRow[NB_P];
  __shared__ int loffCol[NB_P];
  __shared__ int sc[512];
  __shared__ int stg[STG_CAP];
  const int b = (blockIdx.x & (NGRP - 1)) * (NBKT / NGRP) + (blockIdx.x >> 3);
  const int lo = bucketBase[b], hi = bucketBase[b + 1];
  const int cntB = hi - lo;
  const int nodeLo = b * R;
  const int nN = min(R, N - nodeLo);
  const int t = threadIdx.x;
  for (int i = t; i < NB_P; i += SORT_T) {
    offRow[i] = off[b * NB_P + i];
    loffCol[i] = loffG[i * NBKT + b];
  }
  if (t < 512) sc[t] = 0;
  __syncthreads();
  auto fetch = [&](int i) -> int {
    int loQ = 0, hiQ = NB_P;
#pragma unroll
    for (int it = 0; it < 10; ++it) {
      int mid = (loQ + hiQ) >> 1;
      if (offRow[mid] <= i) loQ = mid; else hiQ = mid;
    }
    return epkPriv[(size_t)loQ * CHP + loffCol[loQ] + (i - offRow[loQ])];
  };
  // pass 1: histogram, register-caching pk (static indices -> VGPRs)
  int pkc[RB];
#pragma unroll
  for (int r = 0; r < RB; ++r) {
    const int i = t + r * SORT_T;
    int pk = -1;
    if (i < cntB) {
      pk = fetch(i);
      atomicAdd(&sc[pk >> 17], 1);
    }
    pkc[r] = pk;
  }
  for (int i = t + RB * SORT_T; i < cntB; i += SORT_T) {
    int pk = fetch(i);
    atomicAdd(&sc[pk >> 17], 1);
  }
  __syncthreads();
  int own = (t < 512) ? sc[t] : 0;
  for (int o = 1; o < 512; o <<= 1) {
    int u = (t < 512 && t >= o) ? sc[t - o] : 0;
    __syncthreads();
    if (t < 512) sc[t] += u;
    __syncthreads();
  }
  if (t < nN) rowStart[nodeLo + t] = lo + sc[t] - own;
  if (b == NBKT - 1 && t == 0) rowStart[N] = E;
  if (t < 512) sc[t] -= own;
  __syncthreads();
  // pass 2: placement from cached pk
  if (cntB <= STG_CAP) {
#pragma unroll
    for (int r = 0; r < RB; ++r) {
      const int i = t + r * SORT_T;
      if (i < cntB) {
        int pk = pkc[r];
        int pos = atomicAdd(&sc[pk >> 17], 1);
        stg[pos] = pk & 0x1FFFF;
      }
    }
    for (int i = t + RB * SORT_T; i < cntB; i += SORT_T) {
      int pk = fetch(i);
      int pos = atomicAdd(&sc[pk >> 17], 1);
      stg[pos] = pk & 0x1FFFF;
    }
    __syncthreads();
    for (int i = t; i < cntB; i += SORT_T) colIdx[lo + i] = stg[i];  // coalesced
  } else {
#pragma unroll
    for (int r = 0; r < RB; ++r) {
      const int i = t + r * SORT_T;
      if (i < cntB) {
        int pk = pkc[r];
        int pos = lo + atomicAdd(&sc[pk >> 17], 1);
        colIdx[pos] = pk & 0x1FFFF;
      }
    }
    for (int i = t + RB * SORT_T; i < cntB; i += SORT_T) {
      int pk = fetch(i);
      int pos = lo + atomicAdd(&sc[pk >> 17], 1);
      colIdx[pos] = pk & 0x1FFFF;
    }
  }
}

// ================= edge layer 1 + fused node transform 2 =================
// L=2 x 16B h1 gathers, S=4, masked chunks. Depth-2 pipeline: colIdx 2 ahead,
// h-gathers 1 chunk ahead. as recomputed in-register (1 line/edge).

__global__ void k_edge12(const int* __restrict__ rowStart, const int* __restrict__ colIdx,
                         const _Float16* __restrict__ h1, const float* __restrict__ as1w,
                         const float* __restrict__ ad_, const float* __restrict__ b1,
                         const float* __restrict__ W2, const float* __restrict__ as2w,
                         const float* __restrict__ ad2w, Rec2* __restrict__ r2,
                         float* __restrict__ ad2, int N, int R8) {
  constexpr int L = 2, S = 4, LS = 8, NPB = TB / LS;
  __shared__ float Ws2[128], A1s[16], A2s[8], A2d[8], B1s[16];
  if (threadIdx.x < 128) Ws2[threadIdx.x] = W2[threadIdx.x];
  if (threadIdx.x < 16) {
    A1s[threadIdx.x] = as1w[threadIdx.x];
    B1s[threadIdx.x] = b1[threadIdx.x];
  }
  if (threadIdx.x < 8) {
    A2s[threadIdx.x] = as2w[threadIdx.x];
    A2d[threadIdx.x] = ad2w[threadIdx.x];
  }
  __syncthreads();
  const int g = blockIdx.x & (NGRP - 1);
  const int lb = blockIdx.x / NGRP;
  const int lane = threadIdx.x % LS;
  const int sub = lane >> 1;
  const int j = lane & 1;
  const int n = g * R8 + lb * NPB + threadIdx.x / LS;
  const int nEnd = min((g + 1) * R8, N);
  if (n >= nEnd) return;
  const float adv = ad_[n * 2 + j];
  float aw[8];
#pragma unroll
  for (int c = 0; c < 8; ++c) aw[c] = A1s[j * 8 + c];
  const int start = rowStart[n];
  const int end = rowStart[n + 1];
  float s = 0.f, acc[8];
#pragma unroll
  for (int q = 0; q < 8; ++q) acc[q] = 0.f;
  if (sub == 0) {  // self-loop
    h8v a0 = reinterpret_cast<const h8v*>(h1 + (size_t)n * 16)[j];
    float e = 0.f;
#pragma unroll
    for (int c = 0; c < 8; ++c) e += (float)a0[c] * aw[c];
    float p = __expf(leaky(e + adv));
    s = p;
#pragma unroll
    for (int q = 0; q < 8; ++q) acc[q] = p * (float)a0[q];
  }
  const h8v* hrows = reinterpret_cast<const h8v*>(h1);
  const int base = start & ~3;
  const int nch = (end - base + 3) >> 2;
  const int nmine = (nch > sub) ? ((nch - sub + S - 1) / S) : 0;
  int ti = sub;
  i4v cv0, cv1;
  h8v g0, g1, g2, g3;
  if (nmine >= 1) cv0 = *reinterpret_cast<const i4v*>(colIdx + base + 4 * sub);
  if (nmine >= 2) cv1 = *reinterpret_cast<const i4v*>(colIdx + base + 4 * (sub + S));
  if (nmine >= 1) {
    const int i0 = base + 4 * ti;
    g0 = hrows[(size_t)(((i0 + 0 >= start) && (i0 + 0 < end)) ? cv0[0] : n) * 2 + j];
    g1 = hrows[(size_t)(((i0 + 1 >= start) && (i0 + 1 < end)) ? cv0[1] : n) * 2 + j];
    g2 = hrows[(size_t)(((i0 + 2 >= start) && (i0 + 2 < end)) ? cv0[2] : n) * 2 + j];
    g3 = hrows[(size_t)(((i0 + 3 >= start) && (i0 + 3 < end)) ? cv0[3] : n) * 2 + j];
  }
  for (int m = 0; m < nmine; ++m) {
    const int i0 = base + 4 * ti;
    i4v cv2 = cv1;
    if (m + 2 < nmine) cv2 = *reinterpret_cast<const i4v*>(colIdx + base + 4 * (ti + 2 * S));
    h8v n0 = g0, n1 = g1, n2 = g2, n3 = g3;
    if (m + 1 < nmine) {  // issue next chunk's gathers before computing current
      const int ni0 = base + 4 * (ti + S);
      n0 = hrows[(size_t)(((ni0 + 0 >= start) && (ni0 + 0 < end)) ? cv1[0] : n) * 2 + j];
      n1 = hrows[(size_t)(((ni0 + 1 >= start) && (ni0 + 1 < end)) ? cv1[1] : n) * 2 + j];
      n2 = hrows[(size_t)(((ni0 + 2 >= start) && (ni0 + 2 < end)) ? cv1[2] : n) * 2 + j];
      n3 = hrows[(size_t)(((ni0 + 3 >= start) && (ni0 + 3 < end)) ? cv1[3] : n) * 2 + j];
    }
#pragma unroll
    for (int k = 0; k < 4; ++k) {
      const bool ok = (i0 + k >= start) && (i0 + k < end);
      h8v hv = (k == 0) ? g0 : (k == 1) ? g1 : (k == 2) ? g2 : g3;
      float e = 0.f;
#pragma unroll
      for (int c = 0; c < 8; ++c) e += (float)hv[c] * aw[c];
      float p = ok ? __expf(leaky(e + adv)) : 0.f;
      s += p;
#pragma unroll
      for (int q = 0; q < 8; ++q) acc[q] += p * (float)hv[q];
    }
    cv0 = cv1; cv1 = cv2;
    g0 = n0; g1 = n1; g2 = n2; g3 = n3;
    ti += S;
  }
#pragma unroll
  for (int off = L; off < LS; off <<= 1) {
    s += __shfl_xor(s, off);
#pragma unroll
    for (int q = 0; q < 8; ++q) acc[q] += __shfl_xor(acc[q], off);
  }
  if (sub == 0) {
    float inv = 1.f / (s + 1e-16f);
    float o1v[8];
#pragma unroll
    for (int q = 0; q < 8; ++q) o1v[q] = fmaxf(acc[q] * inv + B1s[j * 8 + q], 0.f);
    float h2p[8];
#pragma unroll
    for (int q = 0; q < 8; ++q) {
      float tacc = 0.f;
#pragma unroll
      for (int c = 0; c < 8; ++c) tacc += o1v[c] * Ws2[(j * 8 + c) * 8 + q];
      h2p[q] = tacc;
    }
    float h2f[8];
#pragma unroll
    for (int q = 0; q < 8; ++q) h2f[q] = h2p[q] + __shfl_xor(h2p[q], 1);
    h4v v;
#pragma unroll
    for (int q = 0; q < 4; ++q) v[q] = (_Float16)h2f[j * 4 + q];
    reinterpret_cast<h4v*>(r2[n].h)[j] = v;
    float ss = 0.f, dd = 0.f;
#pragma unroll
    for (int c = 0; c < 4; ++c) {
      ss += h2f[j * 4 + c] * A2s[j * 4 + c];
      dd += h2f[j * 4 + c] * A2d[j * 4 + c];
    }
    r2[n].as[j] = ss;
    ad2[n * 2 + j] = dd;
  }
}

// ================= edge layer 2 + fused node transform 3 =================
// Depth-2 pipelined Rec2 gathers (h + as from one 32B record).

__global__ void k_edge23(const int* __restrict__ rowStart, const int* __restrict__ colIdx,
                         const Rec2* __restrict__ r2, const float* __restrict__ ad_,
                         const float* __restrict__ b2, const float* __restrict__ W3,
                         const float* __restrict__ as3w, const float* __restrict__ ad3w,
                         Rec3* __restrict__ r3, float* __restrict__ ad3, int N, int R8) {
  constexpr int L = 2, S = 4, LS = 8, NPB = TB / LS;
  __shared__ float Ws3[32], A3s[4], A3d[4], B2s[8];
  if (threadIdx.x < 32) Ws3[threadIdx.x] = W3[threadIdx.x];
  if (threadIdx.x < 4) {
    A3s[threadIdx.x] = as3w[threadIdx.x];
    A3d[threadIdx.x] = ad3w[threadIdx.x];
  }
  if (threadIdx.x < 8) B2s[threadIdx.x] = b2[threadIdx.x];
  __syncthreads();
  const int g = blockIdx.x & (NGRP - 1);
  const int lb = blockIdx.x / NGRP;
  const int lane = threadIdx.x % LS;
  const int sub = lane >> 1;
  const int j = lane & 1;
  const int n = g * R8 + lb * NPB + threadIdx.x / LS;
  const int nEnd = min((g + 1) * R8, N);
  if (n >= nEnd) return;
  const float adv = ad_[n * 2 + j];
  const int start = rowStart[n];
  const int end = rowStart[n + 1];
  float s = 0.f, acc[4];
#pragma unroll
  for (int q = 0; q < 4; ++q) acc[q] = 0.f;
  if (sub == 0) {
    float p = __expf(leaky(r2[n].as[j] + adv));
    h4v a0 = reinterpret_cast<const h4v*>(r2[n].h)[j];
    s = p;
#pragma unroll
    for (int q = 0; q < 4; ++q) acc[q] = p * (float)a0[q];
  }
  const int base = start & ~3;
  const int nch = (end - base + 3) >> 2;
  const int nmine = (nch > sub) ? ((nch - sub + S - 1) / S) : 0;
  int ti = sub;
  i4v cv0, cv1;
  h4v g0, g1, g2, g3;
  float e0, e1, e2, e3;
  auto issue = [&](const i4v& cv, int i0, h4v& o0, h4v& o1, h4v& o2, h4v& o3,
                   float& f0, float& f1, float& f2, float& f3) {
    int s0 = ((i0 + 0 >= start) && (i0 + 0 < end)) ? cv[0] : n;
    int s1 = ((i0 + 1 >= start) && (i0 + 1 < end)) ? cv[1] : n;
    int s2 = ((i0 + 2 >= start) && (i0 + 2 < end)) ? cv[2] : n;
    int s3 = ((i0 + 3 >= start) && (i0 + 3 < end)) ? cv[3] : n;
    o0 = reinterpret_cast<const h4v*>(r2[s0].h)[j]; f0 = r2[s0].as[j];
    o1 = reinterpret_cast<const h4v*>(r2[s1].h)[j]; f1 = r2[s1].as[j];
    o2 = reinterpret_cast<const h4v*>(r2[s2].h)[j]; f2 = r2[s2].as[j];
    o3 = reinterpret_cast<const h4v*>(r2[s3].h)[j]; f3 = r2[s3].as[j];
  };
  if (nmine >= 1) cv0 = *reinterpret_cast<const i4v*>(colIdx + base + 4 * sub);
  if (nmine >= 2) cv1 = *reinterpret_cast<const i4v*>(colIdx + base + 4 * (sub + S));
  if (nmine >= 1) issue(cv0, base + 4 * ti, g0, g1, g2, g3, e0, e1, e2, e3);
  for (int m = 0; m < nmine; ++m) {
    const int i0 = base + 4 * ti;
    i4v cv2 = cv1;
    if (m + 2 < nmine) cv2 = *reinterpret_cast<const i4v*>(colIdx + base + 4 * (ti + 2 * S));
    h4v n0 = g0, n1 = g1, n2 = g2, n3 = g3;
    float f0 = e0, f1 = e1, f2 = e2, f3 = e3;
    if (m + 1 < nmine) issue(cv1, base + 4 * (ti + S), n0, n1, n2, n3, f0, f1, f2, f3);
#pragma unroll
    for (int k = 0; k < 4; ++k) {
      const bool ok = (i0 + k >= start) && (i0 + k < end);
      h4v hv = (k == 0) ? g0 : (k == 1) ? g1 : (k == 2) ? g2 : g3;
      float e = (k == 0) ? e0 : (k == 1) ? e1 : (k == 2) ? e2 : e3;
      float p = ok ? __expf(leaky(e + adv)) : 0.f;
      s += p;
#pragma unroll
      for (int q = 0; q < 4; ++q) acc[q] += p * (float)hv[q];
    }
    cv0 = cv1; cv1 = cv2;
    g0 = n0; g1 = n1; g2 = n2; g3 = n3;
    e0 = f0; e1 = f1; e2 = f2; e3 = f3;
    ti += S;
  }
#pragma unroll
  for (int off = L; off < LS; off <<= 1) {
    s += __shfl_xor(s, off);
#pragma unroll
    for (int q = 0; q < 4; ++q) acc[q] += __shfl_xor(acc[q], off);
  }
  if (sub == 0) {
    float inv = 1.f / (s + 1e-16f);
    float o2v[4];
#pragma unroll
    for (int q = 0; q < 4; ++q) o2v[q] = fmaxf(acc[q] * inv + B2s[j * 4 + q], 0.f);
    float h3p[4];
#pragma unroll
    for (int q = 0; q < 4; ++q) {
      float tacc = 0.f;
#pragma unroll
      for (int c = 0; c < 4; ++c) tacc += o2v[c] * Ws3[(j * 4 + c) * 4 + q];
      h3p[q] = tacc;
    }
    float h3f[4];
#pragma unroll
    for (int q = 0; q < 4; ++q) h3f[q] = h3p[q] + __shfl_xor(h3p[q], 1);
    if (j == 0) {
      Rec3 rec;
#pragma unroll
      for (int q = 0; q < 4; ++q) rec.h[q] = (_Float16)h3f[q];
      float ss = 0.f, dd = 0.f;
#pragma unroll
      for (int c = 0; c < 4; ++c) {
        ss += h3f[c] * A3s[c];
        dd += h3f[c] * A3d[c];
      }
      rec.as = ss;
      rec.pad = 0.f;
      r3[n] = rec;
      ad3[n] = dd;
    }
  }
}

// ================= edge layer 3 + fused classifier; S=8, depth-2 pipeline =================

__global__ void k_edge3(const int* __restrict__ rowStart, const int* __restrict__ colIdx,
                        const Rec3* __restrict__ r3, const float* __restrict__ ad_,
                        const float* __restrict__ b3, const float* __restrict__ Wc,
                        const float* __restrict__ bc, float* __restrict__ out,
                        int N, int R8) {
  constexpr int S = 8;
  constexpr int NPB = TB / S;
  const int g = blockIdx.x & (NGRP - 1);
  const int lb = blockIdx.x / NGRP;
  const int sub = threadIdx.x % S;
  const int n = g * R8 + lb * NPB + threadIdx.x / S;
  const int nEnd = min((g + 1) * R8, N);
  if (n >= nEnd) return;
  const float adv = ad_[n];
  const int start = rowStart[n];
  const int end = rowStart[n + 1];
  float s = 0.f, acc0 = 0.f, acc1 = 0.f, acc2 = 0.f, acc3 = 0.f;
  if (sub == 0) {
    Rec3 rec = r3[n];
    float p = __expf(leaky(rec.as + adv));
    s = p;
    acc0 = p * (float)rec.h[0];
    acc1 = p * (float)rec.h[1];
    acc2 = p * (float)rec.h[2];
    acc3 = p * (float)rec.h[3];
  }
  const int base = start & ~3;
  const int nch = (end - base + 3) >> 2;
  const int nmine = (nch > sub) ? ((nch - sub + S - 1) / S) : 0;
  int ti = sub;
  i4v cv0, cv1;
  Rec3 g0, g1, g2, g3;
  auto issue = [&](const i4v& cv, int i0, Rec3& o0, Rec3& o1, Rec3& o2, Rec3& o3) {
    o0 = r3[((i0 + 0 >= start) && (i0 + 0 < end)) ? cv[0] : n];
    o1 = r3[((i0 + 1 >= start) && (i0 + 1 < end)) ? cv[1] : n];
    o2 = r3[((i0 + 2 >= start) && (i0 + 2 < end)) ? cv[2] : n];
    o3 = r3[((i0 + 3 >= start) && (i0 + 3 < end)) ? cv[3] : n];
  };
  if (nmine >= 1) cv0 = *reinterpret_cast<const i4v*>(colIdx + base + 4 * sub);
  if (nmine >= 2) cv1 = *reinterpret_cast<const i4v*>(colIdx + base + 4 * (sub + S));
  if (nmine >= 1) issue(cv0, base + 4 * ti, g0, g1, g2, g3);
  for (int m = 0; m < nmine; ++m) {
    const int i0 = base + 4 * ti;
    i4v cv2 = cv1;
    if (m + 2 < nmine) cv2 = *reinterpret_cast<const i4v*>(colIdx + base + 4 * (ti + 2 * S));
    Rec3 n0 = g0, n1 = g1, n2 = g2, n3 = g3;
    if (m + 1 < nmine) issue(cv1, base + 4 * (ti + S), n0, n1, n2, n3);
#pragma unroll
    for (int k = 0; k < 4; ++k) {
      const bool ok = (i0 + k >= start) && (i0 + k < end);
      Rec3 rec = (k == 0) ? g0 : (k == 1) ? g1 : (k == 2) ? g2 : g3;
      float p = ok ? __expf(leaky(rec.as + adv)) : 0.f;
      s += p;
      acc0 += p * (float)rec.h[0];
      acc1 += p * (float)rec.h[1];
      acc2 += p * (float)rec.h[2];
      acc3 += p * (float)rec.h[3];
    }
    cv0 = cv1; cv1 = cv2;
    g0 = n0; g1 = n1; g2 = n2; g3 = n3;
    ti += S;
  }
#pragma unroll
  for (int off = 1; off < S; off <<= 1) {
    s += __shfl_xor(s, off);
    acc0 += __shfl_xor(acc0, off);
    acc1 += __shfl_xor(acc1, off);
    acc2 += __shfl_xor(acc2, off);
    acc3 += __shfl_xor(acc3, off);
  }
  if (sub == 0) {
    float inv = 1.f / (s + 1e-16f);
    float o0 = acc0 * inv + b3[0];
    float o1 = acc1 * inv + b3[1];
    float o2 = acc2 * inv + b3[2];
    float o3 = acc3 * inv + b3[3];
    float2 r;
    r.x = o0 * Wc[0] + o1 * Wc[2] + o2 * Wc[4] + o3 * Wc[6] + bc[0];
    r.y = o0 * Wc[1] + o1 * Wc[3] + o2 * Wc[5] + o3 * Wc[7] + bc[1];
    reinterpret_cast<float2*>(out)[n] = r;
  }
}

// ================= launch =================

extern "C" void kernel_launch(void* const* d_in, const int* in_sizes, int n_in,
                              void* d_out, int out_size, void* d_ws, size_t ws_size,
                              hipStream_t stream) {
  const float* x    = (const float*)d_in[0];
  const int*   ei   = (const int*)d_in[1];
  const float* W1   = (const float*)d_in[2];
  const float* as1w = (const float*)d_in[3];
  const float* ad1w = (const float*)d_in[4];
  const float* b1   = (const float*)d_in[5];
  const float* W2   = (const float*)d_in[6];
  const float* as2w = (const float*)d_in[7];
  const float* ad2w = (const float*)d_in[8];
  const float* b2   = (const float*)d_in[9];
  const float* W3   = (const float*)d_in[10];
  const float* as3w = (const float*)d_in[11];
  const float* ad3w = (const float*)d_in[12];
  const float* b3   = (const float*)d_in[13];
  const float* Wc   = (const float*)d_in[14];
  const float* bc   = (const float*)d_in[15];
  float* out = (float*)d_out;

  const int N = in_sizes[0] / 128;
  const int E = in_sizes[1] / 2;
  const int* srcA = ei;
  const int* dstA = ei + E;

  char* p = (char*)d_ws;
  auto alloc = [&](size_t bytes) -> void* {
    void* r = (void*)p;
    p += (bytes + 255) & ~(size_t)255;
    return r;
  };
  const int E4  = E >> 2;
  const int CH4 = (E4 + NB_P - 1) / NB_P;
  const int CHP = CH4 * 4 + 8;

  int* cnt        = (int*)alloc((size_t)NBKT * NB_P * 4);
  int* off        = (int*)alloc((size_t)NBKT * NB_P * 4);
  int* loffG      = (int*)alloc((size_t)NB_P * NBKT * 4);
  int* colTotal   = (int*)alloc(NBKT * 4);
  int* bucketBase = (int*)alloc((NBKT + 1) * 4);
  int* rowStart   = (int*)alloc((size_t)(N + 1) * 4);
  int* epkPriv    = (int*)alloc((size_t)NB_P * CHP * 4);
  int* colIdx     = (int*)alloc((size_t)E * 4 + 256);
  _Float16* h1 = (_Float16*)alloc((size_t)N * 16 * 2);
  float* ad1 = (float*)alloc((size_t)N * 2 * 4);
  Rec2* r2   = (Rec2*)alloc((size_t)N * sizeof(Rec2));
  float* ad2 = (float*)alloc((size_t)N * 2 * 4);
  Rec3* r3   = (Rec3*)alloc((size_t)N * sizeof(Rec3));
  float* ad3 = (float*)alloc((size_t)N * 4);

  const int R   = (N + NBKT - 1) / NBKT;                       // nodes per bucket (391)
  const unsigned M = (unsigned)(((1ULL << 32) + R - 1) / R);   // exact /R via __umulhi
  const int R8  = R * (NBKT / NGRP);                           // nodes per XCD (12512)

  const int nb1 = (N + (TB / 4) - 1) / (TB / 4);   // node1 blocks (SPLIT=4)
  const int ge8 = NGRP * ((R8 + (TB / 8) - 1) / (TB / 8));  // 32 nodes/block

  // single-pass CSR scatter + node1 overlapped in the first dispatch
  k_scatter_node1<<<NB_P + nb1, TB, 0, stream>>>(srcA, dstA, cnt, loffG, epkPriv,
                                                 E4, E, M, R, CH4, CHP,
                                                 x, W1, as1w, ad1w, h1, ad1, N);
  k_bscan1<<<NBKT, NB_P, 0, stream>>>(cnt, off, colTotal);
  k_bscan2<<<1, NBKT, 0, stream>>>(colTotal, bucketBase);
  k_bsort<<<NBKT, SORT_T, 0, stream>>>(epkPriv, off, loffG, bucketBase, rowStart,
                                       colIdx, N, R, E, CHP);

  k_edge12<<<ge8, TB, 0, stream>>>(rowStart, colIdx, h1, as1w, ad1, b1, W2, as2w, ad2w,
                                   r2, ad2, N, R8);
  k_edge23<<<ge8, TB, 0, stream>>>(rowStart, colIdx, r2, ad2, b2, W3, as3w, ad3w,
                                   r3, ad3, N, R8);
  k_edge3<<<ge8, TB, 0, stream>>>(rowStart, colIdx, r3, ad3, b3, Wc, bc, out, N, R8);
}